// Round 16
// baseline (170.265 us; speedup 1.0000x reference)
//
#include <hip/hip_runtime.h>

#define N_NODES   100000
#define N_EDGES   1600000
#define D         128
#define NUM_GRAPHS 128

#define NB          196     // dst buckets (512 nodes each)
#define BUCKET_NODES 512
#define BUCKET_CAP  10240
#define EPB         4096    // edges per binplace block (391 blocks, ~6/CU)

#define N_TILES32   3125    // 100000 / 32 exactly
#define GEMM_BLOCKS 512     // persistent: 2048 waves, 1-2 tiles each
#define GEMM_WAVES  2048

typedef __attribute__((ext_vector_type(8)))  short bf16x8;
typedef __attribute__((ext_vector_type(8)))  unsigned short u16x8;
typedef __attribute__((ext_vector_type(2)))  unsigned int u32x2;
typedef __attribute__((ext_vector_type(4)))  unsigned int u32x4;
typedef __attribute__((ext_vector_type(16))) float f32x16;

__device__ __forceinline__ unsigned short f2bf(float f) {
    unsigned int u = __float_as_uint(f);
    u = (u + 0x7FFFu + ((u >> 16) & 1u)) >> 16;
    return (unsigned short)u;
}

// accumulate 8 fp8 (e4m3) values from an 8-byte word pair into acc[0..7]
__device__ __forceinline__ void acc_f8(float* acc, u32x2 v) {
    auto a0 = __builtin_amdgcn_cvt_pk_f32_fp8((int)v[0], false);
    auto a1 = __builtin_amdgcn_cvt_pk_f32_fp8((int)v[0], true);
    auto a2 = __builtin_amdgcn_cvt_pk_f32_fp8((int)v[1], false);
    auto a3 = __builtin_amdgcn_cvt_pk_f32_fp8((int)v[1], true);
    acc[0] += a0[0]; acc[1] += a0[1]; acc[2] += a1[0]; acc[3] += a1[1];
    acc[4] += a2[0]; acc[5] += a2[1]; acc[6] += a3[0]; acc[7] += a3[1];
}

// 8 fp8 bytes -> bf16x8, exact (e4m3 subset of bf16), via v_perm packing
__device__ __forceinline__ bf16x8 f8_to_bf16x8(u32x2 v) {
    auto f0 = __builtin_amdgcn_cvt_pk_f32_fp8((int)v[0], false);
    auto f1 = __builtin_amdgcn_cvt_pk_f32_fp8((int)v[0], true);
    auto f2 = __builtin_amdgcn_cvt_pk_f32_fp8((int)v[1], false);
    auto f3 = __builtin_amdgcn_cvt_pk_f32_fp8((int)v[1], true);
    u32x4 w;
    w[0] = __builtin_amdgcn_perm(__float_as_uint(f0[1]), __float_as_uint(f0[0]), 0x07060302u);
    w[1] = __builtin_amdgcn_perm(__float_as_uint(f1[1]), __float_as_uint(f1[0]), 0x07060302u);
    w[2] = __builtin_amdgcn_perm(__float_as_uint(f2[1]), __float_as_uint(f2[0]), 0x07060302u);
    w[3] = __builtin_amdgcn_perm(__float_as_uint(f3[1]), __float_as_uint(f3[0]), 0x07060302u);
    return *(bf16x8*)&w;
}

// ---------------- merged small kernels: zero | gcnt | prep_w1 | prep_w2 | cast ----------
// blocks 0..16: zero; 17: gcnt; 18..145: Wt1; 146..273: Wt2; 274..6523: h fp32->fp8
__global__ void k_misc(u32x4* __restrict__ zp, int n16,
                       const int* __restrict__ gid, int* __restrict__ gcnt,
                       const float* __restrict__ W1s, const float* __restrict__ W1n,
                       unsigned short* __restrict__ Wt1,
                       const float* __restrict__ W2s, const float* __restrict__ W2n,
                       unsigned short* __restrict__ Wt2,
                       const float* __restrict__ h, unsigned char* __restrict__ h8) {
    const int b = blockIdx.x;
    if (b < 17) {
        int i = b * 256 + threadIdx.x;
        if (i < n16) zp[i] = (u32x4){0u, 0u, 0u, 0u};
    } else if (b == 17) {
        int g = threadIdx.x;
        if (g >= NUM_GRAPHS) return;
        int lo = 0, hi = N_NODES;
        while (lo < hi) { int mid = (lo + hi) >> 1; if (gid[mid] < g) lo = mid + 1; else hi = mid; }
        int beg = lo;
        hi = N_NODES;
        while (lo < hi) { int mid = (lo + hi) >> 1; if (gid[mid] < g + 1) lo = mid + 1; else hi = mid; }
        gcnt[g] = lo - beg;
    } else if (b < 146) {
        // Wt1[((ct*16+kt)*64+l)*8+j] = W[k][n], n=ct*32+(l&31), k=kt*16+8*(l>>5)+j
        int idx = (b - 18) * 256 + threadIdx.x;
        int j  = idx & 7;
        int l  = (idx >> 3) & 63;
        int fs = idx >> 9;
        int ct = fs >> 4, kt = fs & 15;
        int n  = ct * 32 + (l & 31);
        int k  = kt * 16 + 8 * (l >> 5) + j;
        float v = (k < 128) ? W1s[k * D + n] : W1n[(k - 128) * D + n];
        Wt1[idx] = f2bf(v);
    } else if (b < 274) {
        // Wt2: K axis through sigma^-1: stored pos p holds true col c = 32*(p&3)+(p>>2)
        int idx = (b - 146) * 256 + threadIdx.x;
        int j  = idx & 7;
        int l  = (idx >> 3) & 63;
        int fs = idx >> 9;
        int ct = fs >> 4, kt = fs & 15;
        int n  = ct * 32 + (l & 31);
        int k  = kt * 16 + 8 * (l >> 5) + j;
        int p  = k & 127;
        int c  = 32 * (p & 3) + (p >> 2);
        float v = (k < 128) ? W2s[c * D + n] : W2n[c * D + n];
        Wt2[idx] = f2bf(v);
    } else {
        int i = (b - 274) * 256 + threadIdx.x;
        if (i >= N_NODES * (D / 8)) return;
        const float4* hv = (const float4*)h;
        float4 x = hv[2 * i], y = hv[2 * i + 1];
        int lo = __builtin_amdgcn_cvt_pk_fp8_f32(x.x, x.y, 0, false);
        lo = __builtin_amdgcn_cvt_pk_fp8_f32(x.z, x.w, lo, true);
        int hi = __builtin_amdgcn_cvt_pk_fp8_f32(y.x, y.y, 0, false);
        hi = __builtin_amdgcn_cvt_pk_fp8_f32(y.z, y.w, hi, true);
        u32x2 q; q[0] = (unsigned int)lo; q[1] = (unsigned int)hi;
        *(u32x2*)(h8 + (size_t)i * 8) = q;
    }
}

// ---------------- edge binning: counting-sort into 196 bucket regions ----------------
__global__ __launch_bounds__(256) void k_binplace(const int* __restrict__ src,
                                                  const int* __restrict__ dst,
                                                  int* __restrict__ gcur,
                                                  unsigned int* __restrict__ binned) {
    __shared__ unsigned int stag[EPB];       // 16 KB
    __shared__ unsigned char sbk[EPB];       // 4 KB
    __shared__ int hist[NB], lstart[NB], lcur[NB], gclaim[NB];
    __shared__ int scan[256];
    const int t = threadIdx.x;
    const int e0 = blockIdx.x * EPB;

    if (t < NB) hist[t] = 0;
    __syncthreads();

    int pk[EPB / 256]; int bk[EPB / 256];
#pragma unroll
    for (int i = 0; i < EPB / 256; ++i) {
        int e = e0 + t + 256 * i;
        if (e < N_EDGES) {
            int s = src[e], d = dst[e];
            bk[i] = d >> 9;
            pk[i] = (s << 9) | (d & 511);
            atomicAdd(&hist[bk[i]], 1);
        } else {
            bk[i] = -1; pk[i] = 0;
        }
    }
    __syncthreads();

    int hv = (t < NB) ? hist[t] : 0;
    scan[t] = hv;
    __syncthreads();
    for (int off = 1; off < 256; off <<= 1) {
        int add = (t >= off) ? scan[t - off] : 0;
        __syncthreads();
        scan[t] += add;
        __syncthreads();
    }
    if (t < NB) {
        int ex = scan[t] - hv;
        lstart[t] = ex;
        lcur[t]   = ex;
        gclaim[t] = atomicAdd(&gcur[t], hv);
    }
    __syncthreads();

#pragma unroll
    for (int i = 0; i < EPB / 256; ++i) {
        if (bk[i] >= 0) {
            int p = atomicAdd(&lcur[bk[i]], 1);
            stag[p] = (unsigned int)pk[i];
            sbk[p] = (unsigned char)bk[i];
        }
    }
    __syncthreads();

    const int total = scan[NB - 1];
    for (int j = t; j < total; j += 256) {
        int b = sbk[j];
        binned[(size_t)b * BUCKET_CAP + gclaim[b] + (j - lstart[b])] = stag[j];
    }
}

// ---------------- per-bucket CSR finalize ----------------
__global__ __launch_bounds__(256) void k_fill2(const unsigned int* __restrict__ binned,
                                               const int* __restrict__ gcur,
                                               int* __restrict__ adj,
                                               int* __restrict__ row_start,
                                               int* __restrict__ row_len) {
    __shared__ int hist[BUCKET_NODES], lstart[BUCKET_NODES], lcur[BUCKET_NODES];
    __shared__ int s2[256];
    const int t = threadIdx.x;
    const int b = blockIdx.x;
    const int C = gcur[b];
    const unsigned int* bp = binned + (size_t)b * BUCKET_CAP;

    hist[t] = 0; hist[t + 256] = 0;
    __syncthreads();
    for (int j = t; j < C; j += 256)
        atomicAdd(&hist[bp[j] & 511], 1);
    __syncthreads();

    int h0 = hist[2 * t], h1 = hist[2 * t + 1];
    int sv = h0 + h1;
    s2[t] = sv;
    __syncthreads();
    for (int off = 1; off < 256; off <<= 1) {
        int add = (t >= off) ? s2[t - off] : 0;
        __syncthreads();
        s2[t] += add;
        __syncthreads();
    }
    int ex = s2[t] - sv;
    lstart[2 * t] = ex;          lcur[2 * t] = ex;
    lstart[2 * t + 1] = ex + h0; lcur[2 * t + 1] = ex + h0;
    __syncthreads();

    for (int dl = t; dl < BUCKET_NODES; dl += 256) {
        int n = b * BUCKET_NODES + dl;
        if (n < N_NODES) {
            row_start[n] = b * BUCKET_CAP + lstart[dl];
            row_len[n]   = hist[dl];
        }
    }

    for (int j = t; j < C; j += 256) {
        unsigned int v = bp[j];
        int dl = v & 511;
        int pos = atomicAdd(&lcur[dl], 1);
        adj[(size_t)b * BUCKET_CAP + pos] = (int)(v >> 9);
    }
}

// ---------------- mean aggregation, fp8 in / fp8 out, 8-edge unroll ----------------
__global__ __launch_bounds__(256) void k_agg_f8(const unsigned char* __restrict__ hin,
                                                const int* __restrict__ row_start,
                                                const int* __restrict__ row_len,
                                                const int* __restrict__ adj,
                                                unsigned char* __restrict__ hout) {
    int node = blockIdx.x * 16 + (threadIdx.x >> 4);
    int sub = threadIdx.x & 15;
    if (node >= N_NODES) return;
    int beg = row_start[node];
    int len = row_len[node];
    int end = beg + len;
    const unsigned char* hsub = hin + sub * 8;   // row stride = D bytes (fp8)
    float acc[8];
#pragma unroll
    for (int i = 0; i < 8; ++i) acc[i] = 0.f;
    int j = beg;
    for (; j + 7 < end; j += 8) {
        u32x2 v0 = *(const u32x2*)(hsub + (size_t)adj[j]     * D);
        u32x2 v1 = *(const u32x2*)(hsub + (size_t)adj[j + 1] * D);
        u32x2 v2 = *(const u32x2*)(hsub + (size_t)adj[j + 2] * D);
        u32x2 v3 = *(const u32x2*)(hsub + (size_t)adj[j + 3] * D);
        u32x2 v4 = *(const u32x2*)(hsub + (size_t)adj[j + 4] * D);
        u32x2 v5 = *(const u32x2*)(hsub + (size_t)adj[j + 5] * D);
        u32x2 v6 = *(const u32x2*)(hsub + (size_t)adj[j + 6] * D);
        u32x2 v7 = *(const u32x2*)(hsub + (size_t)adj[j + 7] * D);
        acc_f8(acc, v0); acc_f8(acc, v1); acc_f8(acc, v2); acc_f8(acc, v3);
        acc_f8(acc, v4); acc_f8(acc, v5); acc_f8(acc, v6); acc_f8(acc, v7);
    }
    for (; j + 3 < end; j += 4) {
        u32x2 v0 = *(const u32x2*)(hsub + (size_t)adj[j]     * D);
        u32x2 v1 = *(const u32x2*)(hsub + (size_t)adj[j + 1] * D);
        u32x2 v2 = *(const u32x2*)(hsub + (size_t)adj[j + 2] * D);
        u32x2 v3 = *(const u32x2*)(hsub + (size_t)adj[j + 3] * D);
        acc_f8(acc, v0); acc_f8(acc, v1); acc_f8(acc, v2); acc_f8(acc, v3);
    }
    for (; j < end; ++j) {
        u32x2 v0 = *(const u32x2*)(hsub + (size_t)adj[j] * D);
        acc_f8(acc, v0);
    }
    float inv = (len > 0) ? 1.f / (float)len : 0.f;
    int lo = __builtin_amdgcn_cvt_pk_fp8_f32(acc[0] * inv, acc[1] * inv, 0, false);
    lo = __builtin_amdgcn_cvt_pk_fp8_f32(acc[2] * inv, acc[3] * inv, lo, true);
    int hi = __builtin_amdgcn_cvt_pk_fp8_f32(acc[4] * inv, acc[5] * inv, 0, false);
    hi = __builtin_amdgcn_cvt_pk_fp8_f32(acc[6] * inv, acc[7] * inv, hi, true);
    u32x2 q; q[0] = (unsigned int)lo; q[1] = (unsigned int)hi;
    *(u32x2*)(hout + (size_t)node * D + sub * 8) = q;
}

// ---------------- one 32-row tile: convert + MFMA + epilogue (inlined twice) ----------
template <int POOL>
__device__ __forceinline__ void gemm_tile(
    const u32x2 (&v8)[16], const unsigned short* WS, int gw,
    int lane, int l31, int half,
    const float* __restrict__ bias, unsigned char* __restrict__ outp8,
    const int* __restrict__ gid, float* __restrict__ gsum) {
    bf16x8 a[16];
#pragma unroll
    for (int kt = 0; kt < 16; ++kt) a[kt] = f8_to_bf16x8(v8[kt]);

    f32x16 acc[4];
#pragma unroll
    for (int ct = 0; ct < 4; ++ct)
#pragma unroll
        for (int i = 0; i < 16; ++i) acc[ct][i] = 0.f;

#pragma unroll
    for (int cp = 0; cp < 2; ++cp) {
        const int c0 = 2 * cp, c1 = 2 * cp + 1;
#pragma unroll
        for (int kt = 0; kt < 16; ++kt) {
            bf16x8 b0 = *(const bf16x8*)&WS[((c0 * 16 + kt) * 64 + lane) * 8];
            bf16x8 b1 = *(const bf16x8*)&WS[((c1 * 16 + kt) * 64 + lane) * 8];
            acc[c0] = __builtin_amdgcn_mfma_f32_32x32x16_bf16(a[kt], b0, acc[c0], 0, 0, 0);
            acc[c1] = __builtin_amdgcn_mfma_f32_32x32x16_bf16(a[kt], b1, acc[c1], 0, 0, 0);
        }
    }

    const int trow0 = gw * 32;
    float bia[4];
#pragma unroll
    for (int ct = 0; ct < 4; ++ct) bia[ct] = bias[ct * 32 + l31];

    if (POOL == 0) {
#pragma unroll
        for (int r = 0; r < 16; ++r) {
            int row = trow0 + (r & 3) + 8 * (r >> 2) + 4 * half;
            float f[4];
#pragma unroll
            for (int ct = 0; ct < 4; ++ct)
                f[ct] = fmaxf(acc[ct][r] + bia[ct], 0.f);
            int p8 = __builtin_amdgcn_cvt_pk_fp8_f32(f[0], f[1], 0, false);
            p8 = __builtin_amdgcn_cvt_pk_fp8_f32(f[2], f[3], p8, true);
            *(unsigned int*)(outp8 + (size_t)row * D + l31 * 4) = (unsigned int)p8;
        }
    } else {
        int g[16];
#pragma unroll
        for (int r = 0; r < 16; ++r)
            g[r] = gid[trow0 + (r & 3) + 8 * (r >> 2) + 4 * half];
#pragma unroll
        for (int ct = 0; ct < 4; ++ct) {
            int c = ct * 32 + l31;
            float run = 0.f; int curg = -1;
#pragma unroll
            for (int r = 0; r < 16; ++r) {
                float v = fmaxf(acc[ct][r] + bia[ct], 0.f);
                if (g[r] != curg) {
                    if (curg >= 0) atomicAdd(&gsum[curg * D + c], run);
                    curg = g[r]; run = v;
                } else {
                    run += v;
                }
            }
            if (curg >= 0) atomicAdd(&gsum[curg * D + c], run);
        }
    }
}

// ---------------- persistent MFMA GEMM: 512 blocks, stage W once, 1-2 tiles/wave -----
// Tile-2's raw fp8 A-loads are issued right after the staging barrier, BEFORE tile-1's
// MFMA chain -> they stay in flight under ~2us of compute (in-order vmcnt).
template <int POOL>
__global__ __launch_bounds__(256) void k_gemm_mfma(
    const unsigned char* __restrict__ X0, const unsigned char* __restrict__ X1,
    const unsigned short* __restrict__ Wtp, const float* __restrict__ bias,
    unsigned char* __restrict__ outp8,
    const int* __restrict__ gid, float* __restrict__ gsum) {
    __shared__ unsigned short WS[D * 256];   // 64 KB
    const int tid = threadIdx.x;
    const int wave = tid >> 6, lane = tid & 63;
    const int l31 = lane & 31, half = lane >> 5;
    const int gw0 = blockIdx.x * 4 + wave;       // < 2048, always a valid tile
    const int gw1 = gw0 + GEMM_WAVES;
    const bool has2 = (gw1 < N_TILES32);

    // tile-1 A raw loads (issued before the staging barrier; drained by it for free)
    u32x2 va[16];
    {
        const int row = gw0 * 32 + l31;
        const unsigned char* x0 = X0 + (size_t)row * D + half * 8;
        const unsigned char* x1 = X1 + (size_t)row * D + half * 8;
#pragma unroll
        for (int kt = 0; kt < 8; ++kt) va[kt] = *(const u32x2*)(x0 + kt * 16);
#pragma unroll
        for (int kt = 0; kt < 8; ++kt) va[8 + kt] = *(const u32x2*)(x1 + kt * 16);
    }

    // stage weights -> LDS (64 KB linear)
    {
        const u16x8* g = (const u16x8*)Wtp;
        u16x8* s = (u16x8*)WS;
#pragma unroll
        for (int i = 0; i < 16; ++i) s[i * 256 + tid] = g[i * 256 + tid];
    }
    __syncthreads();

    // tile-2 A raw loads: issue NOW, consume after tile-1's compute
    u32x2 vb[16];
    if (has2) {
        const int row = gw1 * 32 + l31;
        const unsigned char* x0 = X0 + (size_t)row * D + half * 8;
        const unsigned char* x1 = X1 + (size_t)row * D + half * 8;
#pragma unroll
        for (int kt = 0; kt < 8; ++kt) vb[kt] = *(const u32x2*)(x0 + kt * 16);
#pragma unroll
        for (int kt = 0; kt < 8; ++kt) vb[8 + kt] = *(const u32x2*)(x1 + kt * 16);
    }

    gemm_tile<POOL>(va, WS, gw0, lane, l31, half, bias, outp8, gid, gsum);
    if (has2)
        gemm_tile<POOL>(vb, WS, gw1, lane, l31, half, bias, outp8, gid, gsum);
}

// ---------------- final divide ----------------
__global__ void k_final(const float* __restrict__ gsum, const int* __restrict__ gcnt,
                        float* __restrict__ out) {
    int i = blockIdx.x * blockDim.x + threadIdx.x;
    if (i < NUM_GRAPHS * D) {
        int g = i >> 7;
        int c = gcnt[g];
        out[i] = gsum[i] / (float)(c > 0 ? c : 1);
    }
}

// ---------------- launch ----------------
extern "C" void kernel_launch(void* const* d_in, const int* in_sizes, int n_in,
                              void* d_out, int out_size, void* d_ws, size_t ws_size,
                              hipStream_t stream) {
    const float* h   = (const float*)d_in[0];
    const float* W1s = (const float*)d_in[1];
    const float* W1n = (const float*)d_in[2];
    const float* b1  = (const float*)d_in[3];
    const float* W2s = (const float*)d_in[4];
    const float* W2n = (const float*)d_in[5];
    const float* b2  = (const float*)d_in[6];
    const int* src   = (const int*)d_in[7];
    const int* dst   = (const int*)d_in[8];
    const int* gids  = (const int*)d_in[9];
    float* out = (float*)d_out;
    char* ws = (char*)d_ws;

    size_t off = 0;
    auto alloc = [&](size_t bytes) {
        size_t o = off;
        off = (off + bytes + 255) & ~(size_t)255;
        return o;
    };
    // zeroed region (by k_misc blocks 0..16)
    size_t z0         = off;
    size_t gcur_off   = alloc((size_t)NB * 4);
    size_t gsum_off   = alloc((size_t)NUM_GRAPHS * D * 4);
    size_t zlen       = off - z0;
    size_t gcnt_off   = alloc((size_t)NUM_GRAPHS * 4);
    size_t rs_off     = alloc((size_t)N_NODES * 4);
    size_t rl_off     = alloc((size_t)N_NODES * 4);
    size_t bin_off    = alloc((size_t)NB * BUCKET_CAP * 4);
    size_t adj_off    = alloc((size_t)NB * BUCKET_CAP * 4);
    size_t hn_off     = alloc((size_t)N_NODES * D);       // aggregated neigh, fp8
    size_t h8_off     = alloc((size_t)N_NODES * D);       // h fp8
    size_t h18_off    = alloc((size_t)N_NODES * D);       // h1 fp8 (sigma-permuted cols)
    size_t wt1_off    = alloc((size_t)D * 256 * 2);
    size_t wt2_off    = alloc((size_t)D * 256 * 2);
    (void)ws_size;

    int*   gcur      = (int*)(ws + gcur_off);
    int*   gcnt      = (int*)(ws + gcnt_off);
    float* gsum      = (float*)(ws + gsum_off);
    int*   row_start = (int*)(ws + rs_off);
    int*   row_len   = (int*)(ws + rl_off);
    unsigned int* binned = (unsigned int*)(ws + bin_off);
    int*   adj       = (int*)(ws + adj_off);
    unsigned char*  hn8  = (unsigned char*)(ws + hn_off);
    unsigned char*  h8   = (unsigned char*)(ws + h8_off);
    unsigned char*  h1p8 = (unsigned char*)(ws + h18_off);
    unsigned short* Wt1 = (unsigned short*)(ws + wt1_off);
    unsigned short* Wt2 = (unsigned short*)(ws + wt2_off);

    const int n16 = (int)(zlen / 16);   // 17 zero-blocks

    // merged: zero(17) | gcnt(1) | prep_w1(128) | prep_w2(128) | cast(6250) = 6524
    k_misc<<<6524, 256, 0, stream>>>((u32x4*)(ws + z0), n16, gids, gcnt,
                                     W1s, W1n, Wt1, W2s, W2n, Wt2, h, h8);

    const int nbin_blocks = (N_EDGES + EPB - 1) / EPB;   // 391
    k_binplace<<<nbin_blocks, 256, 0, stream>>>(src, dst, gcur, binned);
    k_fill2<<<NB, 256, 0, stream>>>(binned, gcur, adj, row_start, row_len);

    const int agg_blocks = (N_NODES + 15) / 16;    // 6250

    // layer 1
    k_agg_f8<<<agg_blocks, 256, 0, stream>>>(h8, row_start, row_len, adj, hn8);
    k_gemm_mfma<0><<<GEMM_BLOCKS, 256, 0, stream>>>(h8, hn8, Wt1, b1, h1p8,
                                                    nullptr, nullptr);
    // layer 2 (pool fused into epilogue)
    k_agg_f8<<<agg_blocks, 256, 0, stream>>>(h1p8, row_start, row_len, adj, hn8);
    k_gemm_mfma<1><<<GEMM_BLOCKS, 256, 0, stream>>>(h1p8, hn8, Wt2, b2, nullptr,
                                                    gids, gsum);

    k_final<<<(NUM_GRAPHS * D + 255) / 256, 256, 0, stream>>>(gsum, gcnt, out);
}

// Round 18
// 168.709 us; speedup vs baseline: 1.0092x; 1.0092x over previous
//
#include <hip/hip_runtime.h>

#define N_NODES   100000
#define N_EDGES   1600000
#define D         128
#define NUM_GRAPHS 128

#define NB          196     // dst buckets (512 nodes each)
#define BUCKET_NODES 512
#define BUCKET_CAP  10240
#define EPB         4096    // edges per binplace block (391 blocks)

#define N_TILES32   3125    // 100000 / 32 exactly
#define GEMM_BLOCKS 391     // 391 * 8 waves = 3128 >= 3125, one tile per wave

typedef __attribute__((ext_vector_type(8)))  short bf16x8;
typedef __attribute__((ext_vector_type(8)))  unsigned short u16x8;
typedef __attribute__((ext_vector_type(2)))  unsigned int u32x2;
typedef __attribute__((ext_vector_type(4)))  unsigned int u32x4;
typedef __attribute__((ext_vector_type(16))) float f32x16;

__device__ __forceinline__ unsigned short f2bf(float f) {
    unsigned int u = __float_as_uint(f);
    u = (u + 0x7FFFu + ((u >> 16) & 1u)) >> 16;
    return (unsigned short)u;
}

// accumulate 8 fp8 (e4m3) values from an 8-byte word pair into acc[0..7]
__device__ __forceinline__ void acc_f8(float* acc, u32x2 v) {
    auto a0 = __builtin_amdgcn_cvt_pk_f32_fp8((int)v[0], false);
    auto a1 = __builtin_amdgcn_cvt_pk_f32_fp8((int)v[0], true);
    auto a2 = __builtin_amdgcn_cvt_pk_f32_fp8((int)v[1], false);
    auto a3 = __builtin_amdgcn_cvt_pk_f32_fp8((int)v[1], true);
    acc[0] += a0[0]; acc[1] += a0[1]; acc[2] += a1[0]; acc[3] += a1[1];
    acc[4] += a2[0]; acc[5] += a2[1]; acc[6] += a3[0]; acc[7] += a3[1];
}

// 8 fp8 bytes -> bf16x8, exact (e4m3 subset of bf16), via v_perm packing
__device__ __forceinline__ bf16x8 f8_to_bf16x8(u32x2 v) {
    auto f0 = __builtin_amdgcn_cvt_pk_f32_fp8((int)v[0], false);
    auto f1 = __builtin_amdgcn_cvt_pk_f32_fp8((int)v[0], true);
    auto f2 = __builtin_amdgcn_cvt_pk_f32_fp8((int)v[1], false);
    auto f3 = __builtin_amdgcn_cvt_pk_f32_fp8((int)v[1], true);
    u32x4 w;
    w[0] = __builtin_amdgcn_perm(__float_as_uint(f0[1]), __float_as_uint(f0[0]), 0x07060302u);
    w[1] = __builtin_amdgcn_perm(__float_as_uint(f1[1]), __float_as_uint(f1[0]), 0x07060302u);
    w[2] = __builtin_amdgcn_perm(__float_as_uint(f2[1]), __float_as_uint(f2[0]), 0x07060302u);
    w[3] = __builtin_amdgcn_perm(__float_as_uint(f3[1]), __float_as_uint(f3[0]), 0x07060302u);
    return *(bf16x8*)&w;
}

// ---------------- merged small kernels: zero | gcnt | prep_w1 | prep_w2 | cast ----------
// blocks 0..16: zero; 17: gcnt; 18..145: Wt1; 146..273: Wt2; 274..6523: h fp32->fp8
__global__ void k_misc(u32x4* __restrict__ zp, int n16,
                       const int* __restrict__ gid, int* __restrict__ gcnt,
                       const float* __restrict__ W1s, const float* __restrict__ W1n,
                       unsigned short* __restrict__ Wt1,
                       const float* __restrict__ W2s, const float* __restrict__ W2n,
                       unsigned short* __restrict__ Wt2,
                       const float* __restrict__ h, unsigned char* __restrict__ h8) {
    const int b = blockIdx.x;
    if (b < 17) {
        int i = b * 256 + threadIdx.x;
        if (i < n16) zp[i] = (u32x4){0u, 0u, 0u, 0u};
    } else if (b == 17) {
        int g = threadIdx.x;
        if (g >= NUM_GRAPHS) return;
        int lo = 0, hi = N_NODES;
        while (lo < hi) { int mid = (lo + hi) >> 1; if (gid[mid] < g) lo = mid + 1; else hi = mid; }
        int beg = lo;
        hi = N_NODES;
        while (lo < hi) { int mid = (lo + hi) >> 1; if (gid[mid] < g + 1) lo = mid + 1; else hi = mid; }
        gcnt[g] = lo - beg;
    } else if (b < 146) {
        // Wt1[((ct*16+kt)*64+l)*8+j] = W[k][n], n=ct*32+(l&31), k=kt*16+8*(l>>5)+j
        int idx = (b - 18) * 256 + threadIdx.x;
        int j  = idx & 7;
        int l  = (idx >> 3) & 63;
        int fs = idx >> 9;
        int ct = fs >> 4, kt = fs & 15;
        int n  = ct * 32 + (l & 31);
        int k  = kt * 16 + 8 * (l >> 5) + j;
        float v = (k < 128) ? W1s[k * D + n] : W1n[(k - 128) * D + n];
        Wt1[idx] = f2bf(v);
    } else if (b < 274) {
        // Wt2: K axis through sigma^-1: stored pos p holds true col c = 32*(p&3)+(p>>2)
        int idx = (b - 146) * 256 + threadIdx.x;
        int j  = idx & 7;
        int l  = (idx >> 3) & 63;
        int fs = idx >> 9;
        int ct = fs >> 4, kt = fs & 15;
        int n  = ct * 32 + (l & 31);
        int k  = kt * 16 + 8 * (l >> 5) + j;
        int p  = k & 127;
        int c  = 32 * (p & 3) + (p >> 2);
        float v = (k < 128) ? W2s[c * D + n] : W2n[c * D + n];
        Wt2[idx] = f2bf(v);
    } else {
        int i = (b - 274) * 256 + threadIdx.x;
        if (i >= N_NODES * (D / 8)) return;
        const float4* hv = (const float4*)h;
        float4 x = hv[2 * i], y = hv[2 * i + 1];
        int lo = __builtin_amdgcn_cvt_pk_fp8_f32(x.x, x.y, 0, false);
        lo = __builtin_amdgcn_cvt_pk_fp8_f32(x.z, x.w, lo, true);
        int hi = __builtin_amdgcn_cvt_pk_fp8_f32(y.x, y.y, 0, false);
        hi = __builtin_amdgcn_cvt_pk_fp8_f32(y.z, y.w, hi, true);
        u32x2 q; q[0] = (unsigned int)lo; q[1] = (unsigned int)hi;
        *(u32x2*)(h8 + (size_t)i * 8) = q;
    }
}

// ---------------- edge binning: counting-sort into 196 bucket regions ----------------
__global__ __launch_bounds__(256) void k_binplace(const int* __restrict__ src,
                                                  const int* __restrict__ dst,
                                                  int* __restrict__ gcur,
                                                  unsigned int* __restrict__ binned) {
    __shared__ unsigned int stag[EPB];       // 16 KB
    __shared__ unsigned char sbk[EPB];       // 4 KB
    __shared__ int hist[NB], lstart[NB], lcur[NB], gclaim[NB];
    __shared__ int scan[256];
    const int t = threadIdx.x;
    const int e0 = blockIdx.x * EPB;

    if (t < NB) hist[t] = 0;
    __syncthreads();

    int pk[EPB / 256]; int bk[EPB / 256];
#pragma unroll
    for (int i = 0; i < EPB / 256; ++i) {
        int e = e0 + t + 256 * i;
        if (e < N_EDGES) {
            int s = src[e], d = dst[e];
            bk[i] = d >> 9;
            pk[i] = (s << 9) | (d & 511);
            atomicAdd(&hist[bk[i]], 1);
        } else {
            bk[i] = -1; pk[i] = 0;
        }
    }
    __syncthreads();

    int hv = (t < NB) ? hist[t] : 0;
    scan[t] = hv;
    __syncthreads();
    for (int off = 1; off < 256; off <<= 1) {
        int add = (t >= off) ? scan[t - off] : 0;
        __syncthreads();
        scan[t] += add;
        __syncthreads();
    }
    if (t < NB) {
        int ex = scan[t] - hv;
        lstart[t] = ex;
        lcur[t]   = ex;
        gclaim[t] = atomicAdd(&gcur[t], hv);
    }
    __syncthreads();

#pragma unroll
    for (int i = 0; i < EPB / 256; ++i) {
        if (bk[i] >= 0) {
            int p = atomicAdd(&lcur[bk[i]], 1);
            stag[p] = (unsigned int)pk[i];
            sbk[p] = (unsigned char)bk[i];
        }
    }
    __syncthreads();

    const int total = scan[NB - 1];
    for (int j = t; j < total; j += 256) {
        int b = sbk[j];
        binned[(size_t)b * BUCKET_CAP + gclaim[b] + (j - lstart[b])] = stag[j];
    }
}

// ---------------- per-bucket CSR finalize ----------------
__global__ __launch_bounds__(256) void k_fill2(const unsigned int* __restrict__ binned,
                                               const int* __restrict__ gcur,
                                               int* __restrict__ adj,
                                               int* __restrict__ row_start,
                                               int* __restrict__ row_len) {
    __shared__ int hist[BUCKET_NODES], lstart[BUCKET_NODES], lcur[BUCKET_NODES];
    __shared__ int s2[256];
    const int t = threadIdx.x;
    const int b = blockIdx.x;
    const int C = gcur[b];
    const unsigned int* bp = binned + (size_t)b * BUCKET_CAP;

    hist[t] = 0; hist[t + 256] = 0;
    __syncthreads();
    for (int j = t; j < C; j += 256)
        atomicAdd(&hist[bp[j] & 511], 1);
    __syncthreads();

    int h0 = hist[2 * t], h1 = hist[2 * t + 1];
    int sv = h0 + h1;
    s2[t] = sv;
    __syncthreads();
    for (int off = 1; off < 256; off <<= 1) {
        int add = (t >= off) ? s2[t - off] : 0;
        __syncthreads();
        s2[t] += add;
        __syncthreads();
    }
    int ex = s2[t] - sv;
    lstart[2 * t] = ex;          lcur[2 * t] = ex;
    lstart[2 * t + 1] = ex + h0; lcur[2 * t + 1] = ex + h0;
    __syncthreads();

    for (int dl = t; dl < BUCKET_NODES; dl += 256) {
        int n = b * BUCKET_NODES + dl;
        if (n < N_NODES) {
            row_start[n] = b * BUCKET_CAP + lstart[dl];
            row_len[n]   = hist[dl];
        }
    }

    for (int j = t; j < C; j += 256) {
        unsigned int v = bp[j];
        int dl = v & 511;
        int pos = atomicAdd(&lcur[dl], 1);
        adj[(size_t)b * BUCKET_CAP + pos] = (int)(v >> 9);
    }
}

// ---------------- mean aggregation, fp8 in / fp8 out, 8-edge unroll ----------------
__global__ __launch_bounds__(256) void k_agg_f8(const unsigned char* __restrict__ hin,
                                                const int* __restrict__ row_start,
                                                const int* __restrict__ row_len,
                                                const int* __restrict__ adj,
                                                unsigned char* __restrict__ hout) {
    int node = blockIdx.x * 16 + (threadIdx.x >> 4);
    int sub = threadIdx.x & 15;
    if (node >= N_NODES) return;
    int beg = row_start[node];
    int len = row_len[node];
    int end = beg + len;
    const unsigned char* hsub = hin + sub * 8;   // row stride = D bytes (fp8)
    float acc[8];
#pragma unroll
    for (int i = 0; i < 8; ++i) acc[i] = 0.f;
    int j = beg;
    for (; j + 7 < end; j += 8) {
        u32x2 v0 = *(const u32x2*)(hsub + (size_t)adj[j]     * D);
        u32x2 v1 = *(const u32x2*)(hsub + (size_t)adj[j + 1] * D);
        u32x2 v2 = *(const u32x2*)(hsub + (size_t)adj[j + 2] * D);
        u32x2 v3 = *(const u32x2*)(hsub + (size_t)adj[j + 3] * D);
        u32x2 v4 = *(const u32x2*)(hsub + (size_t)adj[j + 4] * D);
        u32x2 v5 = *(const u32x2*)(hsub + (size_t)adj[j + 5] * D);
        u32x2 v6 = *(const u32x2*)(hsub + (size_t)adj[j + 6] * D);
        u32x2 v7 = *(const u32x2*)(hsub + (size_t)adj[j + 7] * D);
        acc_f8(acc, v0); acc_f8(acc, v1); acc_f8(acc, v2); acc_f8(acc, v3);
        acc_f8(acc, v4); acc_f8(acc, v5); acc_f8(acc, v6); acc_f8(acc, v7);
    }
    for (; j + 3 < end; j += 4) {
        u32x2 v0 = *(const u32x2*)(hsub + (size_t)adj[j]     * D);
        u32x2 v1 = *(const u32x2*)(hsub + (size_t)adj[j + 1] * D);
        u32x2 v2 = *(const u32x2*)(hsub + (size_t)adj[j + 2] * D);
        u32x2 v3 = *(const u32x2*)(hsub + (size_t)adj[j + 3] * D);
        acc_f8(acc, v0); acc_f8(acc, v1); acc_f8(acc, v2); acc_f8(acc, v3);
    }
    for (; j < end; ++j) {
        u32x2 v0 = *(const u32x2*)(hsub + (size_t)adj[j] * D);
        acc_f8(acc, v0);
    }
    float inv = (len > 0) ? 1.f / (float)len : 0.f;
    int lo = __builtin_amdgcn_cvt_pk_fp8_f32(acc[0] * inv, acc[1] * inv, 0, false);
    lo = __builtin_amdgcn_cvt_pk_fp8_f32(acc[2] * inv, acc[3] * inv, lo, true);
    int hi = __builtin_amdgcn_cvt_pk_fp8_f32(acc[4] * inv, acc[5] * inv, 0, false);
    hi = __builtin_amdgcn_cvt_pk_fp8_f32(acc[6] * inv, acc[7] * inv, hi, true);
    u32x2 q; q[0] = (unsigned int)lo; q[1] = (unsigned int)hi;
    *(u32x2*)(hout + (size_t)node * D + sub * 8) = q;
}

// ---------------- MFMA GEMM: 512-thr/8-wave blocks, low-VGPR 2-pass accumulator ------
// 391 blocks x 8 waves, one 32-row tile per wave. 64 KB W staged once per block
// (amortized over 8 waves). VGPR kept <=128 via __launch_bounds__(512,4):
//   - A held as raw fp8 (va[16] = 32 VGPR), converted per-kt on the fly (VALU
//     overlaps the MFMA pipe)
//   - accumulator split into 2 passes of 2 ct-chains (32 VGPR), per-pass epilogue
// -> 2 blocks/CU * 8 waves = 16 waves/CU, 2x R15's latency hiding.
// A-frag: row = lane&31, k = kt*16 + 8*(lane>>5) + j.
// C/D:    col = lane&31, row = (reg&3) + 8*(reg>>2) + 4*(lane>>5).
// POOL=0: fp8 store, cols sigma-permuted: byte pos l31*4+ct holds col ct*32+l31
//         (per pass: one 2-byte store at l31*4+2cp).
// POOL=1: run-compressed per-graph atomics at true cols.
template <int POOL>
__global__ __launch_bounds__(512, 4) void k_gemm_mfma(
    const unsigned char* __restrict__ X0, const unsigned char* __restrict__ X1,
    const unsigned short* __restrict__ Wtp, const float* __restrict__ bias,
    unsigned char* __restrict__ outp8,
    const int* __restrict__ gid, float* __restrict__ gsum) {
    __shared__ unsigned short WS[D * 256];   // 64 KB
    const int tid = threadIdx.x;
    const int wave = tid >> 6, lane = tid & 63;
    const int l31 = lane & 31, half = lane >> 5;
    const int gw = blockIdx.x * 8 + wave;    // 32-row tile id
    const bool act = (gw < N_TILES32);

    // raw fp8 A loads first (latency hidden under the staging barrier)
    u32x2 va[16];
    if (act) {
        const int row = gw * 32 + l31;
        const unsigned char* x0 = X0 + (size_t)row * D + half * 8;
        const unsigned char* x1 = X1 + (size_t)row * D + half * 8;
#pragma unroll
        for (int kt = 0; kt < 8; ++kt) va[kt] = *(const u32x2*)(x0 + kt * 16);
#pragma unroll
        for (int kt = 0; kt < 8; ++kt) va[8 + kt] = *(const u32x2*)(x1 + kt * 16);
    }

    // stage weights -> LDS (64 KB linear, 128 B/thread)
    {
        const u16x8* g = (const u16x8*)Wtp;
        u16x8* s = (u16x8*)WS;
#pragma unroll
        for (int i = 0; i < 8; ++i) s[i * 512 + tid] = g[i * 512 + tid];
    }
    __syncthreads();
    if (!act) return;

    const int trow0 = gw * 32;

#pragma unroll 1
    for (int cp = 0; cp < 2; ++cp) {
        const int c0 = 2 * cp, c1 = 2 * cp + 1;
        f32x16 acc0, acc1;
#pragma unroll
        for (int i = 0; i < 16; ++i) { acc0[i] = 0.f; acc1[i] = 0.f; }

#pragma unroll
        for (int kt = 0; kt < 16; ++kt) {
            bf16x8 a  = f8_to_bf16x8(va[kt]);
            bf16x8 b0 = *(const bf16x8*)&WS[((c0 * 16 + kt) * 64 + lane) * 8];
            bf16x8 b1 = *(const bf16x8*)&WS[((c1 * 16 + kt) * 64 + lane) * 8];
            acc0 = __builtin_amdgcn_mfma_f32_32x32x16_bf16(a, b0, acc0, 0, 0, 0);
            acc1 = __builtin_amdgcn_mfma_f32_32x32x16_bf16(a, b1, acc1, 0, 0, 0);
        }

        float bia0 = bias[c0 * 32 + l31];
        float bia1 = bias[c1 * 32 + l31];

        if (POOL == 0) {
#pragma unroll
            for (int r = 0; r < 16; ++r) {
                int row = trow0 + (r & 3) + 8 * (r >> 2) + 4 * half;
                float f0 = fmaxf(acc0[r] + bia0, 0.f);
                float f1 = fmaxf(acc1[r] + bia1, 0.f);
                int p8 = __builtin_amdgcn_cvt_pk_fp8_f32(f0, f1, 0, false);
                *(unsigned short*)(outp8 + (size_t)row * D + l31 * 4 + cp * 2) =
                    (unsigned short)(p8 & 0xFFFF);
            }
        } else {
            float run0 = 0.f, run1 = 0.f; int curg = -1;
            const int cc0 = c0 * 32 + l31, cc1 = c1 * 32 + l31;
#pragma unroll
            for (int r = 0; r < 16; ++r) {
                int g = gid[trow0 + (r & 3) + 8 * (r >> 2) + 4 * half];
                float v0 = fmaxf(acc0[r] + bia0, 0.f);
                float v1 = fmaxf(acc1[r] + bia1, 0.f);
                if (g != curg) {
                    if (curg >= 0) {
                        atomicAdd(&gsum[curg * D + cc0], run0);
                        atomicAdd(&gsum[curg * D + cc1], run1);
                    }
                    curg = g; run0 = v0; run1 = v1;
                } else {
                    run0 += v0; run1 += v1;
                }
            }
            if (curg >= 0) {
                atomicAdd(&gsum[curg * D + cc0], run0);
                atomicAdd(&gsum[curg * D + cc1], run1);
            }
        }
    }
}

// ---------------- final divide ----------------
__global__ void k_final(const float* __restrict__ gsum, const int* __restrict__ gcnt,
                        float* __restrict__ out) {
    int i = blockIdx.x * blockDim.x + threadIdx.x;
    if (i < NUM_GRAPHS * D) {
        int g = i >> 7;
        int c = gcnt[g];
        out[i] = gsum[i] / (float)(c > 0 ? c : 1);
    }
}

// ---------------- launch ----------------
extern "C" void kernel_launch(void* const* d_in, const int* in_sizes, int n_in,
                              void* d_out, int out_size, void* d_ws, size_t ws_size,
                              hipStream_t stream) {
    const float* h   = (const float*)d_in[0];
    const float* W1s = (const float*)d_in[1];
    const float* W1n = (const float*)d_in[2];
    const float* b1  = (const float*)d_in[3];
    const float* W2s = (const float*)d_in[4];
    const float* W2n = (const float*)d_in[5];
    const float* b2  = (const float*)d_in[6];
    const int* src   = (const int*)d_in[7];
    const int* dst   = (const int*)d_in[8];
    const int* gids  = (const int*)d_in[9];
    float* out = (float*)d_out;
    char* ws = (char*)d_ws;

    size_t off = 0;
    auto alloc = [&](size_t bytes) {
        size_t o = off;
        off = (off + bytes + 255) & ~(size_t)255;
        return o;
    };
    // zeroed region (by k_misc blocks 0..16)
    size_t z0         = off;
    size_t gcur_off   = alloc((size_t)NB * 4);
    size_t gsum_off   = alloc((size_t)NUM_GRAPHS * D * 4);
    size_t zlen       = off - z0;
    size_t gcnt_off   = alloc((size_t)NUM_GRAPHS * 4);
    size_t rs_off     = alloc((size_t)N_NODES * 4);
    size_t rl_off     = alloc((size_t)N_NODES * 4);
    size_t bin_off    = alloc((size_t)NB * BUCKET_CAP * 4);
    size_t adj_off    = alloc((size_t)NB * BUCKET_CAP * 4);
    size_t hn_off     = alloc((size_t)N_NODES * D);       // aggregated neigh, fp8
    size_t h8_off     = alloc((size_t)N_NODES * D);       // h fp8
    size_t h18_off    = alloc((size_t)N_NODES * D);       // h1 fp8 (sigma-permuted cols)
    size_t wt1_off    = alloc((size_t)D * 256 * 2);
    size_t wt2_off    = alloc((size_t)D * 256 * 2);
    (void)ws_size;

    int*   gcur      = (int*)(ws + gcur_off);
    int*   gcnt      = (int*)(ws + gcnt_off);
    float* gsum      = (float*)(ws + gsum_off);
    int*   row_start = (int*)(ws + rs_off);
    int*   row_len   = (int*)(ws + rl_off);
    unsigned int* binned = (unsigned int*)(ws + bin_off);
    int*   adj       = (int*)(ws + adj_off);
    unsigned char*  hn8  = (unsigned char*)(ws + hn_off);
    unsigned char*  h8   = (unsigned char*)(ws + h8_off);
    unsigned char*  h1p8 = (unsigned char*)(ws + h18_off);
    unsigned short* Wt1 = (unsigned short*)(ws + wt1_off);
    unsigned short* Wt2 = (unsigned short*)(ws + wt2_off);

    const int n16 = (int)(zlen / 16);   // 17 zero-blocks

    // merged: zero(17) | gcnt(1) | prep_w1(128) | prep_w2(128) | cast(6250) = 6524
    k_misc<<<6524, 256, 0, stream>>>((u32x4*)(ws + z0), n16, gids, gcnt,
                                     W1s, W1n, Wt1, W2s, W2n, Wt2, h, h8);

    const int nbin_blocks = (N_EDGES + EPB - 1) / EPB;   // 391
    k_binplace<<<nbin_blocks, 256, 0, stream>>>(src, dst, gcur, binned);
    k_fill2<<<NB, 256, 0, stream>>>(binned, gcur, adj, row_start, row_len);

    const int agg_blocks = (N_NODES + 15) / 16;    // 6250

    // layer 1
    k_agg_f8<<<agg_blocks, 256, 0, stream>>>(h8, row_start, row_len, adj, hn8);
    k_gemm_mfma<0><<<GEMM_BLOCKS, 512, 0, stream>>>(h8, hn8, Wt1, b1, h1p8,
                                                    nullptr, nullptr);
    // layer 2 (pool fused into epilogue)
    k_agg_f8<<<agg_blocks, 256, 0, stream>>>(h1p8, row_start, row_len, adj, hn8);
    k_gemm_mfma<1><<<GEMM_BLOCKS, 512, 0, stream>>>(h1p8, hn8, Wt2, b2, nullptr,
                                                    gids, gsum);

    k_final<<<(NUM_GRAPHS * D + 255) / 256, 256, 0, stream>>>(gsum, gcnt, out);
}